// Round 5
// baseline (131.002 us; speedup 1.0000x reference)
//
#include <hip/hip_runtime.h>

// B=8, S=4096, E=256, H=4, DK=64. Tokens = 32768.
// Head-mix "attention": 4 GEMMs (32768x256 @ 256x256) + per-token 4x4 softmax.
// Round-5 = round-4 with the O-loop dbuf prefetch bug fixed:
//   distance-2 prefetch must target WB[(kk+2)&1] == WB[cur], AFTER the MFMAs
//   that consume WB[cur] (round-4 wrote WB[nxt], clobbering kk+1's frags).

typedef __bf16 bf16x8 __attribute__((ext_vector_type(8)));
typedef __bf16 bf16x4 __attribute__((ext_vector_type(4)));
typedef float f32x4 __attribute__((ext_vector_type(4)));

#define LDW 264   // LDS row stride (bf16): 264*2=528 B, 16B-aligned rows

#define MFMA(a, b, c) __builtin_amdgcn_mfma_f32_16x16x32_bf16((a), (b), (c), 0, 0, 0)

// ---------- prep: pack W into fragment-contiguous bf16 ----------
// frag (p,nw,nf,kk): lane (lh=lane&15, lq=lane>>4) holds
//   W_p[nw*64+nf*16+lh][kk*32+lq*8 .. +8)  (16 B)
// at Wpk[frag_id*512 + lane*8], frag_id = ((p*4+nw)*4+nf)*8+kk.
__global__ void pack_wfrag(const float* __restrict__ Wq, const float* __restrict__ Wk,
                           const float* __restrict__ Wv, const float* __restrict__ Wo,
                           __bf16* __restrict__ Wpk) {
  const int f    = blockIdx.x;          // 0..511
  const int lane = threadIdx.x;         // 0..63
  const int kk = f & 7;
  const int nf = (f >> 3) & 3;
  const int nw = (f >> 5) & 3;
  const int p  = f >> 7;
  const float* W = (p == 0) ? Wq : (p == 1) ? Wk : (p == 2) ? Wv : Wo;
  const int lh = lane & 15, lq = lane >> 4;
  const int n  = nw * 64 + nf * 16 + lh;
  const int k0 = kk * 32 + lq * 8;
  const float4 s0 = *(const float4*)&W[n * 256 + k0];
  const float4 s1 = *(const float4*)&W[n * 256 + k0 + 4];
  bf16x8 r;
  r[0] = (__bf16)s0.x; r[1] = (__bf16)s0.y; r[2] = (__bf16)s0.z; r[3] = (__bf16)s0.w;
  r[4] = (__bf16)s1.x; r[5] = (__bf16)s1.y; r[6] = (__bf16)s1.z; r[7] = (__bf16)s1.w;
  *(bf16x8*)&Wpk[(size_t)f * 512 + lane * 8] = r;
}

__device__ __forceinline__ void store_cd(__bf16* __restrict__ buf, const f32x4 acc[2][4],
                                         const float* __restrict__ bias,
                                         int n0, int lh, int lq) {
  #pragma unroll
  for (int nf = 0; nf < 4; ++nf) {
    int col = n0 + nf * 16 + lh;
    float bb = bias[col];
    #pragma unroll
    for (int mf = 0; mf < 2; ++mf) {
      int r = mf * 16 + lq * 4;
      #pragma unroll
      for (int j = 0; j < 4; ++j)
        buf[(r + j) * LDW + col] = (__bf16)(acc[mf][nf][j] + bb);
    }
  }
}

__launch_bounds__(256, 3)
__global__ void fused_attn(const float* __restrict__ x, const __bf16* __restrict__ Wpk,
                           const float* __restrict__ bq, const float* __restrict__ bk,
                           const float* __restrict__ bv, const float* __restrict__ bo,
                           float* __restrict__ out) {
  __shared__ __bf16 xs[32 * LDW];    // x tile, then V
  __shared__ __bf16 qs[32 * LDW];    // Q
  __shared__ __bf16 ksh[32 * LDW];   // K, then Y
  __shared__ float PL[32 * 16];

  const int tid  = threadIdx.x;
  const int lane = tid & 63;
  const int nw   = tid >> 6;
  const int lh   = lane & 15;
  const int lq   = lane >> 4;
  const int n0   = nw * 64;
  const int tok0 = blockIdx.x * 32;

  // ---- stage x: lane-contiguous float4 -> bf16 padded LDS ----
  const float4* xg = (const float4*)(x + (size_t)tok0 * 256);
  #pragma unroll
  for (int i = 0; i < 8; ++i) {
    int idx = i * 256 + tid;
    int row = idx >> 6;
    int c4  = idx & 63;
    float4 v = xg[idx];
    bf16x4 pk;
    pk[0] = (__bf16)v.x; pk[1] = (__bf16)v.y; pk[2] = (__bf16)v.z; pk[3] = (__bf16)v.w;
    *(bf16x4*)&xs[row * LDW + c4 * 4] = pk;
  }
  __syncthreads();

  const __bf16* a0p = xs + lh * LDW + lq * 8;
  const __bf16* a1p = a0p + 16 * LDW;
  // packed bases; frag offset for (nf,kk) = (nf*8+kk)*512
  const __bf16* wqB = Wpk + (size_t)((0 * 4 + nw) * 4 * 8) * 512 + lane * 8;
  const __bf16* wkB = Wpk + (size_t)((1 * 4 + nw) * 4 * 8) * 512 + lane * 8;
  const __bf16* wvB = Wpk + (size_t)((2 * 4 + nw) * 4 * 8) * 512 + lane * 8;
  const __bf16* woB = Wpk + (size_t)((3 * 4 + nw) * 4 * 8) * 512 + lane * 8;

  // ---- merged Q+K loop, distance-1 dbuf prefetch (into just-consumed buf's
  //      partner: WQ[nxt] holds kk-1, already dead) ----
  f32x4 qa[2][4], ka[2][4];
  #pragma unroll
  for (int mf = 0; mf < 2; ++mf)
    #pragma unroll
    for (int nf = 0; nf < 4; ++nf) {
      qa[mf][nf] = (f32x4){0.f, 0.f, 0.f, 0.f};
      ka[mf][nf] = (f32x4){0.f, 0.f, 0.f, 0.f};
    }
  {
    bf16x8 WQ[2][4], WK[2][4];
    #pragma unroll
    for (int nf = 0; nf < 4; ++nf) {
      WQ[0][nf] = *(const bf16x8*)(wqB + (nf * 8 + 0) * 512);
      WK[0][nf] = *(const bf16x8*)(wkB + (nf * 8 + 0) * 512);
    }
    #pragma unroll
    for (int kk = 0; kk < 8; ++kk) {
      const int cur = kk & 1, nxt = cur ^ 1;
      if (kk < 7) {
        #pragma unroll
        for (int nf = 0; nf < 4; ++nf) {
          WQ[nxt][nf] = *(const bf16x8*)(wqB + (nf * 8 + kk + 1) * 512);
          WK[nxt][nf] = *(const bf16x8*)(wkB + (nf * 8 + kk + 1) * 512);
        }
      }
      bf16x8 a0 = *(const bf16x8*)(a0p + kk * 32);
      bf16x8 a1 = *(const bf16x8*)(a1p + kk * 32);
      #pragma unroll
      for (int nf = 0; nf < 4; ++nf) {
        qa[0][nf] = MFMA(a0, WQ[cur][nf], qa[0][nf]);
        qa[1][nf] = MFMA(a1, WQ[cur][nf], qa[1][nf]);
        ka[0][nf] = MFMA(a0, WK[cur][nf], ka[0][nf]);
        ka[1][nf] = MFMA(a1, WK[cur][nf], ka[1][nf]);
      }
    }
  }
  store_cd(qs, qa, bq, n0, lh, lq);
  store_cd(ksh, ka, bk, n0, lh, lq);

  // ---- V loop (reads xs; result kept in regs until after barrier) ----
  f32x4 va[2][4];
  #pragma unroll
  for (int mf = 0; mf < 2; ++mf)
    #pragma unroll
    for (int nf = 0; nf < 4; ++nf) va[mf][nf] = (f32x4){0.f, 0.f, 0.f, 0.f};
  {
    bf16x8 WV[2][4];
    #pragma unroll
    for (int nf = 0; nf < 4; ++nf)
      WV[0][nf] = *(const bf16x8*)(wvB + (nf * 8 + 0) * 512);
    #pragma unroll
    for (int kk = 0; kk < 8; ++kk) {
      const int cur = kk & 1, nxt = cur ^ 1;
      if (kk < 7) {
        #pragma unroll
        for (int nf = 0; nf < 4; ++nf)
          WV[nxt][nf] = *(const bf16x8*)(wvB + (nf * 8 + kk + 1) * 512);
      }
      bf16x8 a0 = *(const bf16x8*)(a0p + kk * 32);
      bf16x8 a1 = *(const bf16x8*)(a1p + kk * 32);
      #pragma unroll
      for (int nf = 0; nf < 4; ++nf) {
        va[0][nf] = MFMA(a0, WV[cur][nf], va[0][nf]);
        va[1][nf] = MFMA(a1, WV[cur][nf], va[1][nf]);
      }
    }
  }
  __syncthreads();   // all xs A-reads done; Q,K visible

  // ---- V -> xs (x dead), softmax in same phase ----
  store_cd(xs, va, bv, n0, lh, lq);
  {
    const int m   = tid >> 3;
    const int sub = tid & 7;
    if (sub < 4) {
      const int h = sub;
      float d0 = 0.f, d1 = 0.f, d2 = 0.f, d3 = 0.f;
      #pragma unroll
      for (int i = 0; i < 8; ++i) {
        bf16x8 qv = *(const bf16x8*)&qs[m * LDW + h * 64 + i * 8];
        bf16x8 k0 = *(const bf16x8*)&ksh[m * LDW +   0 + i * 8];
        bf16x8 k1 = *(const bf16x8*)&ksh[m * LDW +  64 + i * 8];
        bf16x8 k2 = *(const bf16x8*)&ksh[m * LDW + 128 + i * 8];
        bf16x8 k3 = *(const bf16x8*)&ksh[m * LDW + 192 + i * 8];
        #pragma unroll
        for (int j = 0; j < 8; ++j) {
          float qf = (float)qv[j];
          d0 += qf * (float)k0[j];
          d1 += qf * (float)k1[j];
          d2 += qf * (float)k2[j];
          d3 += qf * (float)k3[j];
        }
      }
      d0 *= 0.125f; d1 *= 0.125f; d2 *= 0.125f; d3 *= 0.125f;  // 1/sqrt(64)
      float mx = fmaxf(fmaxf(d0, d1), fmaxf(d2, d3));
      float e0 = expf(d0 - mx), e1 = expf(d1 - mx), e2 = expf(d2 - mx), e3 = expf(d3 - mx);
      float inv = 1.0f / (e0 + e1 + e2 + e3);
      float* pl = &PL[m * 16 + h * 4];
      pl[0] = e0 * inv; pl[1] = e1 * inv; pl[2] = e2 * inv; pl[3] = e3 * inv;
    }
  }
  __syncthreads();   // V + PL visible; Q,K reads complete

  // ---- prefetch first two O k-slices (overlaps ymix + barrier drain) ----
  bf16x8 WB[2][4];
  #pragma unroll
  for (int nf = 0; nf < 4; ++nf) {
    WB[0][nf] = *(const bf16x8*)(woB + (nf * 8 + 0) * 512);
    WB[1][nf] = *(const bf16x8*)(woB + (nf * 8 + 1) * 512);
  }

  // ---- y-mix: Y -> ksh (K dead) ----
  {
    const int m   = tid >> 3;
    const int sub = tid & 7;
    const int h   = sub >> 1;
    const int c0  = (sub & 1) * 32;
    const float p0 = PL[m * 16 + h * 4 + 0];
    const float p1 = PL[m * 16 + h * 4 + 1];
    const float p2 = PL[m * 16 + h * 4 + 2];
    const float p3 = PL[m * 16 + h * 4 + 3];
    #pragma unroll
    for (int dd = 0; dd < 32; dd += 8) {
      int c = c0 + dd;
      bf16x8 v0 = *(const bf16x8*)&xs[m * LDW +   0 + c];
      bf16x8 v1 = *(const bf16x8*)&xs[m * LDW +  64 + c];
      bf16x8 v2 = *(const bf16x8*)&xs[m * LDW + 128 + c];
      bf16x8 v3 = *(const bf16x8*)&xs[m * LDW + 192 + c];
      bf16x8 yv;
      #pragma unroll
      for (int j = 0; j < 8; ++j) {
        float f = p0 * (float)v0[j] + p1 * (float)v1[j]
                + p2 * (float)v2[j] + p3 * (float)v3[j];
        yv[j] = (__bf16)f;
      }
      *(bf16x8*)&ksh[m * LDW + h * 64 + c] = yv;
    }
  }
  __syncthreads();   // Y visible

  // ---- O-GEMM: out = Y @ Wo^T + bo ----
  // Distance-2 prefetch: consume WB[cur], THEN load kk+2 into WB[cur]
  // ((kk+2)&1 == cur). Source order guarantees old values feed the MFMAs;
  // compiler renames + hoists the independent loads for pipelining.
  {
    const __bf16* yp0 = &ksh[lh * LDW + lq * 8];
    const __bf16* yp1 = &ksh[(16 + lh) * LDW + lq * 8];
    f32x4 acc[2][4];
    #pragma unroll
    for (int mf = 0; mf < 2; ++mf)
      #pragma unroll
      for (int nf = 0; nf < 4; ++nf) acc[mf][nf] = (f32x4){0.f, 0.f, 0.f, 0.f};

    #pragma unroll
    for (int kk = 0; kk < 8; ++kk) {
      const int cur = kk & 1;
      bf16x8 a0 = *(const bf16x8*)(yp0 + kk * 32);
      bf16x8 a1 = *(const bf16x8*)(yp1 + kk * 32);
      #pragma unroll
      for (int nf = 0; nf < 4; ++nf) {
        acc[0][nf] = MFMA(a0, WB[cur][nf], acc[0][nf]);
        acc[1][nf] = MFMA(a1, WB[cur][nf], acc[1][nf]);
      }
      if (kk < 6) {
        #pragma unroll
        for (int nf = 0; nf < 4; ++nf)
          WB[cur][nf] = *(const bf16x8*)(woB + (nf * 8 + kk + 2) * 512);
      }
    }

    #pragma unroll
    for (int nf = 0; nf < 4; ++nf) {
      int col = n0 + nf * 16 + lh;
      float bb = bo[col];
      #pragma unroll
      for (int mf = 0; mf < 2; ++mf) {
        int rbase = tok0 + mf * 16 + lq * 4;
        #pragma unroll
        for (int j = 0; j < 4; ++j)
          out[(size_t)(rbase + j) * 256 + col] = acc[mf][nf][j] + bb;
      }
    }
  }
}

extern "C" void kernel_launch(void* const* d_in, const int* in_sizes, int n_in,
                              void* d_out, int out_size, void* d_ws, size_t ws_size,
                              hipStream_t stream) {
  const float* x  = (const float*)d_in[0];
  const float* Wq = (const float*)d_in[1];
  const float* bq = (const float*)d_in[2];
  const float* Wk = (const float*)d_in[3];
  const float* bk = (const float*)d_in[4];
  const float* Wv = (const float*)d_in[5];
  const float* bv = (const float*)d_in[6];
  const float* Wo = (const float*)d_in[7];
  const float* bo = (const float*)d_in[8];
  float* out = (float*)d_out;
  __bf16* Wpk = (__bf16*)d_ws;   // 512 frags x 1 KB

  pack_wfrag<<<dim3(512), dim3(64), 0, stream>>>(Wq, Wk, Wv, Wo, Wpk);
  fused_attn<<<dim3(1024), dim3(256), 0, stream>>>(x, Wpk, bq, bk, bv, bo, out);
}